// Round 6
// baseline (790.645 us; speedup 1.0000x reference)
//
#include <hip/hip_runtime.h>
#include <hip/hip_bf16.h>

// Problem constants
#define B_  32
#define NI_ 1024
#define NT_ 512
#define D_  1024

typedef __attribute__((ext_vector_type(8))) short bf16x8;   // 8 bf16 = 4 VGPRs
typedef __attribute__((ext_vector_type(4))) float f32x4;    // MFMA accumulator

// round-to-nearest-even f32 -> bf16 (values are finite here)
__device__ __forceinline__ ushort f2b(float f) {
  unsigned u = __builtin_bit_cast(unsigned, f);
  u = (u + 0x7FFFu + ((u >> 16) & 1u)) >> 16;
  return (ushort)u;
}

// ---------------------------------------------------------------------------
// LDS tile scheme (reg-staged, XOR-swizzled; fixes R3's 4-way read conflict
// while keeping writes conflict-free):
//   A [rows][32] bf16 tile is stored as 16-row blocks of 64 16B-chunks.
//   Chunk for (row, kc):  pos = blk*64 + (row&15)*4 + (kc ^ ((row>>1)&3))
//   Staging thread t loads global (row = base + t>>2, kc = t&3) -> write pos
//   from t: wpos = ((t>>6)<<6) | (((t>>2)&15)<<2) | ((t&3) ^ ((t>>3)&3)).
//   MFMA frag read lane l, block bi: chunk = bi*64 + chunkLane, with
//   chunkLane = ((l&15)<<2) | ((l>>4) ^ ((l>>1)&3)).
//   Banks: writes cover all 32 banks per 8-lane group (0 conflict); reads are
//   2-way (free, m136).
// ---------------------------------------------------------------------------

// ---------------------------------------------------------------------------
// LayerNorm over D=1024, fp32 in -> bf16 out. One wave per row, 4 rows/block.
// ---------------------------------------------------------------------------
__global__ __launch_bounds__(256) void ln_bf16_kernel(
    const float* __restrict__ x, const float* __restrict__ gamma,
    const float* __restrict__ beta, ushort* __restrict__ out)
{
  const int row  = blockIdx.x * 4 + (threadIdx.x >> 6);
  const int lane = threadIdx.x & 63;
  const float* xr = x + (size_t)row * D_;
  float4 v[4];
  float s = 0.f, sq = 0.f;
#pragma unroll
  for (int q = 0; q < 4; ++q) {
    v[q] = *reinterpret_cast<const float4*>(xr + q * 256 + lane * 4);
    s  += v[q].x + v[q].y + v[q].z + v[q].w;
    sq += v[q].x*v[q].x + v[q].y*v[q].y + v[q].z*v[q].z + v[q].w*v[q].w;
  }
#pragma unroll
  for (int m = 1; m < 64; m <<= 1) {
    s  += __shfl_xor(s,  m);
    sq += __shfl_xor(sq, m);
  }
  const float mean = s * (1.f / D_);
  const float rstd = rsqrtf(sq * (1.f / D_) - mean * mean + 1e-5f);
  ushort* orow = out + (size_t)row * D_;
#pragma unroll
  for (int q = 0; q < 4; ++q) {
    const float4 g  = *reinterpret_cast<const float4*>(gamma + q * 256 + lane * 4);
    const float4 bt = *reinterpret_cast<const float4*>(beta  + q * 256 + lane * 4);
    ushort4 o;
    o.x = f2b((v[q].x - mean) * rstd * g.x + bt.x);
    o.y = f2b((v[q].y - mean) * rstd * g.y + bt.y);
    o.z = f2b((v[q].z - mean) * rstd * g.z + bt.z);
    o.w = f2b((v[q].w - mean) * rstd * g.w + bt.w);
    *reinterpret_cast<ushort4*>(orow + q * 256 + lane * 4) = o;
  }
}

// ---------------------------------------------------------------------------
// bf16 transpose [R][C] -> [C][R], per batch. 64x64 LDS tile.
// grid (C/64, R/64, B), block 256.
// ---------------------------------------------------------------------------
__global__ __launch_bounds__(256) void transpose_bf16_kernel(
    const ushort* __restrict__ in, ushort* __restrict__ out, int R, int C)
{
  __shared__ ushort lds[64][68];
  const size_t nb = (size_t)blockIdx.z * (size_t)R * C;
  const ushort* ib = in + nb;
  ushort* ob = out + nb;
  const int c0 = blockIdx.x * 64, r0 = blockIdx.y * 64;
  const int t = threadIdx.x;
#pragma unroll
  for (int it = 0; it < 2; ++it) {
    const int r = (t >> 3) + 32 * it;
    const int c = (t & 7) * 8;
    uint4 val = *reinterpret_cast<const uint4*>(ib + (size_t)(r0 + r) * C + c0 + c);
    *reinterpret_cast<uint2*>(&lds[r][c])     = make_uint2(val.x, val.y);
    *reinterpret_cast<uint2*>(&lds[r][c + 4]) = make_uint2(val.z, val.w);
  }
  __syncthreads();
#pragma unroll
  for (int it = 0; it < 2; ++it) {
    const int c  = (t >> 3) + 32 * it;  // output row = original col
    const int rb = (t & 7) * 8;         // original row chunk
    union { ushort u[8]; uint4 v; } pk;
#pragma unroll
    for (int j = 0; j < 8; ++j) pk.u[j] = lds[rb + j][c];
    *reinterpret_cast<uint4*>(ob + (size_t)(c0 + c) * R + r0 + rb) = pk.v;
  }
}

// ---------------------------------------------------------------------------
// qk_softmax v6: reg-staged (R3 structure, the empirical best), XOR-swizzled
// LDS (conflict-free), 2-deep register prefetch. Block = 64 i x 512 t,
// 8 waves (each 64i x 64t). Grid 512 blocks, XCD-swizzled.
// ---------------------------------------------------------------------------
__global__ __launch_bounds__(512) void qk_softmax_kernel(
    const ushort* __restrict__ qn,   // [B][NI][D] bf16
    const ushort* __restrict__ kn,   // [B][NT][D] bf16
    ushort* __restrict__ attn_it,    // [B][NI][NT] bf16
    ushort* __restrict__ attn_ti)    // [B][NT][NI] bf16
{
  __shared__ __align__(16) ushort Asm[2][64 * 32];     // 2 x 4KB
  __shared__ __align__(16) ushort Bsm[2][512 * 32];    // 2 x 32KB
  __shared__ __align__(16) float redm[64][8];
  __shared__ __align__(16) float reds[64][8];

  // bijective XCD swizzle (512 blocks, 64 per XCD = 4 consecutive batches)
  const int bid = blockIdx.x;
  const int sid = (bid & 7) * 64 + (bid >> 3);
  const int b   = sid >> 4;            // batch
  const int i0  = (sid & 15) * 64;     // i-block base
  const int tid  = threadIdx.x;
  const int w    = tid >> 6;           // wave 0..7 -> t-range w*64
  const int lane = tid & 63;
  const int lr   = lane & 15;
  const int g    = lane >> 4;

  const ushort* qb = qn + ((size_t)b * NI_ + i0) * D_;
  const ushort* kb = kn + (size_t)b * NT_ * D_;

  const int srow = tid >> 2;
  const int scol = (tid & 3) * 8;
  // swizzled write position (16B-chunk index) and frag-read chunk
  const int wpos = ((tid >> 6) << 6) | (((tid >> 2) & 15) << 2)
                 | ((tid & 3) ^ ((tid >> 3) & 3));
  const int chunkLane = ((lane & 15) << 2) | ((lane >> 4) ^ ((lane >> 1) & 3));

  struct QT { uint4 a, b0, b1, b2, b3; };
  QT rA, rB;
  auto LOAD = [&](int t, QT& r) {
    const int ko = t * 32 + scol;
    if (tid < 256) r.a = *reinterpret_cast<const uint4*>(qb + (size_t)srow * D_ + ko);
    r.b0 = *reinterpret_cast<const uint4*>(kb + (size_t)(srow      ) * D_ + ko);
    r.b1 = *reinterpret_cast<const uint4*>(kb + (size_t)(srow + 128) * D_ + ko);
    r.b2 = *reinterpret_cast<const uint4*>(kb + (size_t)(srow + 256) * D_ + ko);
    r.b3 = *reinterpret_cast<const uint4*>(kb + (size_t)(srow + 384) * D_ + ko);
  };
  auto WRITE = [&](int nb, QT& r) {
    const int wp = wpos * 8;
    if (tid < 256) *reinterpret_cast<uint4*>(&Asm[nb][wp]) = r.a;
    *reinterpret_cast<uint4*>(&Bsm[nb][wp         ]) = r.b0;
    *reinterpret_cast<uint4*>(&Bsm[nb][wp +  4096 ]) = r.b1;  // +512 chunks
    *reinterpret_cast<uint4*>(&Bsm[nb][wp +  8192 ]) = r.b2;
    *reinterpret_cast<uint4*>(&Bsm[nb][wp + 12288 ]) = r.b3;
  };

  f32x4 acc[4][4];
#pragma unroll
  for (int i = 0; i < 4; ++i)
#pragma unroll
    for (int j = 0; j < 4; ++j) acc[i][j] = (f32x4){0.f, 0.f, 0.f, 0.f};

  auto MFMA = [&](int nb) {
    const ushort* As = Asm[nb];
    const ushort* Bs = Bsm[nb];
    bf16x8 af[4], bf[4];
#pragma unroll
    for (int i = 0; i < 4; ++i)
      af[i] = *reinterpret_cast<const bf16x8*>(As + (i * 64 + chunkLane) * 8);
#pragma unroll
    for (int j = 0; j < 4; ++j)
      bf[j] = *reinterpret_cast<const bf16x8*>(Bs + (((w * 4 + j) * 64 + chunkLane)) * 8);
#pragma unroll
    for (int i = 0; i < 4; ++i)
#pragma unroll
      for (int j = 0; j < 4; ++j)
        acc[i][j] = __builtin_amdgcn_mfma_f32_16x16x32_bf16(af[i], bf[j], acc[i][j], 0, 0, 0);
  };

  const int nst = D_ / 32;   // 32 (even)
  LOAD(0, rA); WRITE(0, rA);
  LOAD(1, rB);
  __syncthreads();
  for (int t = 0; t < nst; t += 2) {
    // even: compute buf0 (tile t); rB holds t+1; prefetch t+2 -> rA
    if (t + 2 < nst) LOAD(t + 2, rA);
    MFMA(0);
    __syncthreads();
    WRITE(1, rB);            // tile t+1 (t+1 < nst always: nst even)
    __syncthreads();
    // odd: compute buf1 (tile t+1); rA holds t+2; prefetch t+3 -> rB
    if (t + 3 < nst) LOAD(t + 3, rB);
    MFMA(1);
    __syncthreads();
    if (t + 2 < nst) WRITE(0, rA);
    __syncthreads();
  }

  // ---- softmax over full t (512) per i-row ----
  // C/D: row(i) = i*16 + g*4 + r, col(t) = w*64 + j*16 + lr
  const float c1 = 0.03125f * 1.44269504f;  // scale * log2(e)

  float mx[4][4];
#pragma unroll
  for (int i = 0; i < 4; ++i)
#pragma unroll
    for (int r = 0; r < 4; ++r) {
      float m = fmaxf(fmaxf(acc[i][0][r], acc[i][1][r]),
                      fmaxf(acc[i][2][r], acc[i][3][r]));
      m = fmaxf(m, __shfl_xor(m, 1));
      m = fmaxf(m, __shfl_xor(m, 2));
      m = fmaxf(m, __shfl_xor(m, 4));
      m = fmaxf(m, __shfl_xor(m, 8));
      mx[i][r] = m;
    }
  if (lr == 0) {
#pragma unroll
    for (int i = 0; i < 4; ++i)
#pragma unroll
      for (int r = 0; r < 4; ++r) redm[i * 16 + g * 4 + r][w] = mx[i][r];
  }
  __syncthreads();
  float gm[4][4];
#pragma unroll
  for (int i = 0; i < 4; ++i)
#pragma unroll
    for (int r = 0; r < 4; ++r) {
      const int row = i * 16 + g * 4 + r;
      const float4 a0 = *reinterpret_cast<const float4*>(&redm[row][0]);
      const float4 a1 = *reinterpret_cast<const float4*>(&redm[row][4]);
      gm[i][r] = fmaxf(fmaxf(fmaxf(a0.x, a0.y), fmaxf(a0.z, a0.w)),
                       fmaxf(fmaxf(a1.x, a1.y), fmaxf(a1.z, a1.w)));
    }

  float sm[4][4];
#pragma unroll
  for (int i = 0; i < 4; ++i)
#pragma unroll
    for (int r = 0; r < 4; ++r) sm[i][r] = 0.f;
#pragma unroll
  for (int i = 0; i < 4; ++i)
#pragma unroll
    for (int j = 0; j < 4; ++j)
#pragma unroll
      for (int r = 0; r < 4; ++r) {
        const float p = exp2f((acc[i][j][r] - gm[i][r]) * c1);
        acc[i][j][r] = p;
        sm[i][r] += p;
      }
#pragma unroll
  for (int i = 0; i < 4; ++i)
#pragma unroll
    for (int r = 0; r < 4; ++r) {
      float s = sm[i][r];
      s += __shfl_xor(s, 1);
      s += __shfl_xor(s, 2);
      s += __shfl_xor(s, 4);
      s += __shfl_xor(s, 8);
      sm[i][r] = s;
    }
  if (lr == 0) {
#pragma unroll
    for (int i = 0; i < 4; ++i)
#pragma unroll
      for (int r = 0; r < 4; ++r) reds[i * 16 + g * 4 + r][w] = sm[i][r];
  }
  __syncthreads();
  float inv[4][4];
#pragma unroll
  for (int i = 0; i < 4; ++i)
#pragma unroll
    for (int r = 0; r < 4; ++r) {
      const int row = i * 16 + g * 4 + r;
      const float4 a0 = *reinterpret_cast<const float4*>(&reds[row][0]);
      const float4 a1 = *reinterpret_cast<const float4*>(&reds[row][4]);
      inv[i][r] = 1.f / (a0.x + a0.y + a0.z + a0.w + a1.x + a1.y + a1.z + a1.w);
    }

  // ---- write attn in both layouts ----
#pragma unroll
  for (int i = 0; i < 4; ++i) {
    const int rbase = i0 + i * 16 + g * 4;
#pragma unroll
    for (int j = 0; j < 4; ++j) {
      const int tcol = w * 64 + j * 16 + lr;
      ushort4 pk;
      pk.x = f2b(acc[i][j][0] * inv[i][0]);
      pk.y = f2b(acc[i][j][1] * inv[i][1]);
      pk.z = f2b(acc[i][j][2] * inv[i][2]);
      pk.w = f2b(acc[i][j][3] * inv[i][3]);
      ushort* it_p = attn_it + ((size_t)b * NI_ + rbase) * NT_ + tcol;
      it_p[0 * NT_] = pk.x;
      it_p[1 * NT_] = pk.y;
      it_p[2 * NT_] = pk.z;
      it_p[3 * NT_] = pk.w;
      *reinterpret_cast<ushort4*>(attn_ti + ((size_t)b * NT_ + tcol) * NI_ + rbase) = pk;
    }
  }
}

// ---------------------------------------------------------------------------
// bt_gemm v5: C[m][n] = add[m][n] + sum_k A[m][k]*Bm[n][k].
// Reg-staged (R3 structure), XOR-swizzled LDS (conflict-free), 2-deep
// register prefetch. BK=32, 128x128 tile, 4 waves 2x2.
// grid (N/128, M/128, B), block 256.
// ---------------------------------------------------------------------------
__global__ __launch_bounds__(256) void bt_gemm_add_kernel(
    const ushort* __restrict__ A,   // [B][M][K] bf16
    const ushort* __restrict__ Bm,  // [B][N][K] bf16
    const float* __restrict__ add,  // [B][M][N] f32
    float* __restrict__ out,        // [B][M][N] f32
    int M, int N, int K)
{
  __shared__ __align__(16) ushort Asm[2][128 * 32];   // 2 x 8KB
  __shared__ __align__(16) ushort Bsm[2][128 * 32];   // 2 x 8KB

  const int b    = blockIdx.z;
  const int m0   = blockIdx.y * 128;
  const int n0   = blockIdx.x * 128;
  const int tid  = threadIdx.x;
  const int w    = tid >> 6;
  const int lane = tid & 63;
  const int lr   = lane & 15;
  const int g    = lane >> 4;

  const ushort* Ab = A  + ((size_t)b * M + m0) * K;
  const ushort* Bb = Bm + ((size_t)b * N + n0) * K;

  const int srow = tid >> 2;           // 0..63
  const int scol = (tid & 3) * 8;
  const int wpos = ((tid >> 6) << 6) | (((tid >> 2) & 15) << 2)
                 | ((tid & 3) ^ ((tid >> 3) & 3));
  const int chunkLane = ((lane & 15) << 2) | ((lane >> 4) ^ ((lane >> 1) & 3));

  struct GT { uint4 a0, a1, b0, b1; };
  GT rA, rB;
  auto LOAD = [&](int t, GT& r) {
    const int ko = t * 32 + scol;
    r.a0 = *reinterpret_cast<const uint4*>(Ab + (size_t)(srow     ) * K + ko);
    r.a1 = *reinterpret_cast<const uint4*>(Ab + (size_t)(srow + 64) * K + ko);
    r.b0 = *reinterpret_cast<const uint4*>(Bb + (size_t)(srow     ) * K + ko);
    r.b1 = *reinterpret_cast<const uint4*>(Bb + (size_t)(srow + 64) * K + ko);
  };
  auto WRITE = [&](int nb, GT& r) {
    const int wp = wpos * 8;
    *reinterpret_cast<uint4*>(&Asm[nb][wp       ]) = r.a0;
    *reinterpret_cast<uint4*>(&Asm[nb][wp + 2048]) = r.a1;  // +256 chunks
    *reinterpret_cast<uint4*>(&Bsm[nb][wp       ]) = r.b0;
    *reinterpret_cast<uint4*>(&Bsm[nb][wp + 2048]) = r.b1;
  };

  f32x4 acc[4][4];
#pragma unroll
  for (int i = 0; i < 4; ++i)
#pragma unroll
    for (int j = 0; j < 4; ++j) acc[i][j] = (f32x4){0.f, 0.f, 0.f, 0.f};

  auto MFMA = [&](int nb) {
    const ushort* As = Asm[nb];
    const ushort* Bs = Bsm[nb];
    bf16x8 af[4], bf[4];
#pragma unroll
    for (int i = 0; i < 4; ++i)
      af[i] = *reinterpret_cast<const bf16x8*>(
          As + ((((w >> 1) * 4 + i) * 64 + chunkLane)) * 8);
#pragma unroll
    for (int j = 0; j < 4; ++j)
      bf[j] = *reinterpret_cast<const bf16x8*>(
          Bs + ((((w & 1) * 4 + j) * 64 + chunkLane)) * 8);
#pragma unroll
    for (int i = 0; i < 4; ++i)
#pragma unroll
      for (int j = 0; j < 4; ++j)
        acc[i][j] = __builtin_amdgcn_mfma_f32_16x16x32_bf16(af[i], bf[j], acc[i][j], 0, 0, 0);
  };

  const int nst = K / 32;   // 16 or 32 (even)
  LOAD(0, rA); WRITE(0, rA);
  LOAD(1, rB);
  __syncthreads();
  for (int t = 0; t < nst; t += 2) {
    if (t + 2 < nst) LOAD(t + 2, rA);
    MFMA(0);
    __syncthreads();
    WRITE(1, rB);
    __syncthreads();
    if (t + 3 < nst) LOAD(t + 3, rB);
    MFMA(1);
    __syncthreads();
    if (t + 2 < nst) WRITE(0, rA);
    __syncthreads();
  }

  const size_t ob = (size_t)b * M * N;
  const int rbase = m0 + (w >> 1) * 64 + g * 4;
#pragma unroll
  for (int i = 0; i < 4; ++i)
#pragma unroll
    for (int j = 0; j < 4; ++j) {
      const int c = n0 + (w & 1) * 64 + j * 16 + lr;
#pragma unroll
      for (int r = 0; r < 4; ++r) {
        const size_t idx = ob + (size_t)(rbase + i * 16 + r) * N + c;
        out[idx] = add[idx] + acc[i][j][r];
      }
    }
}

// ---------------------------------------------------------------------------
// Schedule (with buffer aliasing; requires ws_size >= 96 MB; observed ~768MB):
//   imn  (bf16 image_norm)  lives in out1 region of d_out
//   txn  (bf16 text_norm)   lives in out0 region of d_out (dead before out0)
//   ws: [attn_ti 32MB][attn_it 32MB][txnorm_T 32MB]; imnorm_T (64MB) reuses
//       attn_it+txnorm_T slots after the first GEMM consumes them.
// ---------------------------------------------------------------------------
extern "C" void kernel_launch(void* const* d_in, const int* in_sizes, int n_in,
                              void* d_out, int out_size, void* d_ws, size_t ws_size,
                              hipStream_t stream) {
  const float* imgf  = (const float*)d_in[0];
  const float* txtf  = (const float*)d_in[1];
  const float* gamma = (const float*)d_in[2];
  const float* beta  = (const float*)d_in[3];

  float* out0 = (float*)d_out;                       // [B][NI][D] f32
  float* out1 = out0 + (size_t)B_ * NI_ * D_;        // [B][NT][D] f32

  const size_t SZ = (size_t)B_ * NT_ * NI_ * 2;      // 33,554,432 B
  char* ws = (char*)d_ws;
  ushort* attn_ti = (ushort*)ws;                     // [B][NT][NI]
  ushort* attn_it = (ushort*)(ws + SZ);              // [B][NI][NT]
  ushort* txnT    = (ushort*)(ws + 2 * SZ);          // [B][D][NT]
  ushort* imnT    = (ushort*)(ws + SZ);              // [B][D][NI] (aliases attn_it+txnT)
  ushort* imn     = (ushort*)out1;                   // [B][NI][D] bf16 (scratch in out1)
  ushort* txn     = (ushort*)out0;                   // [B][NT][D] bf16 (scratch in out0)

  // 1-2: layernorms -> bf16
  ln_bf16_kernel<<<(B_ * NI_) / 4, 256, 0, stream>>>(imgf, gamma, beta, imn);
  ln_bf16_kernel<<<(B_ * NT_) / 4, 256, 0, stream>>>(txtf, gamma, beta, txn);
  // 3: QK^T + softmax -> attn in both layouts (512 blocks, XCD-swizzled)
  qk_softmax_kernel<<<(NI_ / 64) * B_, 512, 0, stream>>>(imn, txn, attn_it, attn_ti);
  // 4: text_norm^T
  transpose_bf16_kernel<<<dim3(D_ / 64, NT_ / 64, B_), 256, 0, stream>>>(txn, txnT, NT_, D_);
  // 5: out0 = image + attn @ text_norm   (overwrites txn scratch — dead)
  bt_gemm_add_kernel<<<dim3(D_ / 128, NI_ / 128, B_), 256, 0, stream>>>(
      attn_it, txnT, imgf, out0, NI_, D_, NT_);
  // 6: image_norm^T (overwrites attn_it + txnT — dead)
  transpose_bf16_kernel<<<dim3(D_ / 64, NI_ / 64, B_), 256, 0, stream>>>(imn, imnT, NI_, D_);
  // 7: out1 = text + attn^T @ image_norm (overwrites imn scratch — dead)
  bt_gemm_add_kernel<<<dim3(D_ / 128, NT_ / 128, B_), 256, 0, stream>>>(
      attn_ti, imnT, txtf, out1, NT_, D_, NI_);
}

// Round 7
// 334.451 us; speedup vs baseline: 2.3640x; 2.3640x over previous
//
#include <hip/hip_runtime.h>
#include <hip/hip_bf16.h>

// Problem constants
#define B_  32
#define NI_ 1024
#define NT_ 512
#define D_  1024

typedef __attribute__((ext_vector_type(8))) short bf16x8;   // 8 bf16 = 4 VGPRs
typedef __attribute__((ext_vector_type(4))) float f32x4;    // MFMA accumulator

// round-to-nearest-even f32 -> bf16 (values are finite here)
__device__ __forceinline__ ushort f2b(float f) {
  unsigned u = __builtin_bit_cast(unsigned, f);
  u = (u + 0x7FFFu + ((u >> 16) & 1u)) >> 16;
  return (ushort)u;
}

// ---------------------------------------------------------------------------
// LDS tile scheme (XOR-swizzled chunk order; bank-verified in R6):
//   A [rows][32] bf16 tile is 16-row blocks of 64 16B-chunks.
//   Chunk for (row,kc): pos = (row>>4)*64 + (row&15)*4 + (kc ^ ((row>>1)&3)).
//   Staging thread t (chunk c=t: row=c>>2, kc=c&3) writes at
//     wpos = ((t>>6)<<6) | (((t>>2)&15)<<2) | ((t&3) ^ ((t>>3)&3)).
//   MFMA frag read lane l, block bi: chunk = bi*64 + chunkLane,
//     chunkLane = ((l&15)<<2) | ((l>>4) ^ ((l>>1)&3)).
//   Every 8 consecutive threads/lanes cover all 32 banks exactly once ->
//   both ds_write_b128 and ds_read_b128 conflict-free (R3 had 4-way reads:
//   4.2M SQ_LDS_BANK_CONFLICT).
// ---------------------------------------------------------------------------

// ---------------------------------------------------------------------------
// LayerNorm over D=1024, fp32 in -> bf16 out. One wave per row, 4 rows/block.
// ---------------------------------------------------------------------------
__global__ __launch_bounds__(256) void ln_bf16_kernel(
    const float* __restrict__ x, const float* __restrict__ gamma,
    const float* __restrict__ beta, ushort* __restrict__ out)
{
  const int row  = blockIdx.x * 4 + (threadIdx.x >> 6);
  const int lane = threadIdx.x & 63;
  const float* xr = x + (size_t)row * D_;
  float4 v[4];
  float s = 0.f, sq = 0.f;
#pragma unroll
  for (int q = 0; q < 4; ++q) {
    v[q] = *reinterpret_cast<const float4*>(xr + q * 256 + lane * 4);
    s  += v[q].x + v[q].y + v[q].z + v[q].w;
    sq += v[q].x*v[q].x + v[q].y*v[q].y + v[q].z*v[q].z + v[q].w*v[q].w;
  }
#pragma unroll
  for (int m = 1; m < 64; m <<= 1) {
    s  += __shfl_xor(s,  m);
    sq += __shfl_xor(sq, m);
  }
  const float mean = s * (1.f / D_);
  const float rstd = rsqrtf(sq * (1.f / D_) - mean * mean + 1e-5f);
  ushort* orow = out + (size_t)row * D_;
#pragma unroll
  for (int q = 0; q < 4; ++q) {
    const float4 g  = *reinterpret_cast<const float4*>(gamma + q * 256 + lane * 4);
    const float4 bt = *reinterpret_cast<const float4*>(beta  + q * 256 + lane * 4);
    ushort4 o;
    o.x = f2b((v[q].x - mean) * rstd * g.x + bt.x);
    o.y = f2b((v[q].y - mean) * rstd * g.y + bt.y);
    o.z = f2b((v[q].z - mean) * rstd * g.z + bt.z);
    o.w = f2b((v[q].w - mean) * rstd * g.w + bt.w);
    *reinterpret_cast<ushort4*>(orow + q * 256 + lane * 4) = o;
  }
}

// ---------------------------------------------------------------------------
// bf16 transpose [R][C] -> [C][R], per batch. 64x64 LDS tile.
// grid (C/64, R/64, B), block 256.
// ---------------------------------------------------------------------------
__global__ __launch_bounds__(256) void transpose_bf16_kernel(
    const ushort* __restrict__ in, ushort* __restrict__ out, int R, int C)
{
  __shared__ ushort lds[64][68];
  const size_t nb = (size_t)blockIdx.z * (size_t)R * C;
  const ushort* ib = in + nb;
  ushort* ob = out + nb;
  const int c0 = blockIdx.x * 64, r0 = blockIdx.y * 64;
  const int t = threadIdx.x;
#pragma unroll
  for (int it = 0; it < 2; ++it) {
    const int r = (t >> 3) + 32 * it;
    const int c = (t & 7) * 8;
    uint4 val = *reinterpret_cast<const uint4*>(ib + (size_t)(r0 + r) * C + c0 + c);
    *reinterpret_cast<uint2*>(&lds[r][c])     = make_uint2(val.x, val.y);
    *reinterpret_cast<uint2*>(&lds[r][c + 4]) = make_uint2(val.z, val.w);
  }
  __syncthreads();
#pragma unroll
  for (int it = 0; it < 2; ++it) {
    const int c  = (t >> 3) + 32 * it;  // output row = original col
    const int rb = (t & 7) * 8;         // original row chunk
    union { ushort u[8]; uint4 v; } pk;
#pragma unroll
    for (int j = 0; j < 8; ++j) pk.u[j] = lds[rb + j][c];
    *reinterpret_cast<uint4*>(ob + (size_t)(c0 + c) * R + r0 + rb) = pk.v;
  }
}

// ---------------------------------------------------------------------------
// qk_softmax v7: R3 reg-staged double-buffer structure (the empirical best),
// ONLY change: XOR-swizzled LDS chunk order (conflict-free reads+writes).
// Block = 64 i x 512 t, 8 waves (each 64i x 64t). Grid 512, XCD-swizzled.
// ---------------------------------------------------------------------------
__global__ __launch_bounds__(512) void qk_softmax_kernel(
    const ushort* __restrict__ qn,   // [B][NI][D] bf16
    const ushort* __restrict__ kn,   // [B][NT][D] bf16
    ushort* __restrict__ attn_it,    // [B][NI][NT] bf16
    ushort* __restrict__ attn_ti)    // [B][NT][NI] bf16
{
  __shared__ __align__(16) ushort Asm[2][64 * 32];     // 2 x 4KB
  __shared__ __align__(16) ushort Bsm[2][512 * 32];    // 2 x 32KB
  __shared__ __align__(16) float redm[64][8];
  __shared__ __align__(16) float reds[64][8];

  // bijective XCD swizzle (512 blocks, 64 per XCD = 4 consecutive batches)
  const int bid = blockIdx.x;
  const int sid = (bid & 7) * 64 + (bid >> 3);
  const int b   = sid >> 4;            // batch
  const int i0  = (sid & 15) * 64;     // i-block base
  const int tid  = threadIdx.x;
  const int w    = tid >> 6;           // wave 0..7 -> t-range w*64
  const int lane = tid & 63;
  const int lr   = lane & 15;
  const int g    = lane >> 4;

  const ushort* qb = qn + ((size_t)b * NI_ + i0) * D_;
  const ushort* kb = kn + (size_t)b * NT_ * D_;

  const int srow = tid >> 2;
  const int scol = (tid & 3) * 8;
  const int wp = (((tid >> 6) << 6) | (((tid >> 2) & 15) << 2)
                | ((tid & 3) ^ ((tid >> 3) & 3))) * 8;
  const int chunkLane = ((lane & 15) << 2) | ((lane >> 4) ^ ((lane >> 1) & 3));

  uint4 ra, rb0, rb1, rb2, rb3;
  auto LOAD = [&](int t) {
    const int ko = t * 32 + scol;
    if (tid < 256) ra = *reinterpret_cast<const uint4*>(qb + (size_t)srow * D_ + ko);
    rb0 = *reinterpret_cast<const uint4*>(kb + (size_t)(srow      ) * D_ + ko);
    rb1 = *reinterpret_cast<const uint4*>(kb + (size_t)(srow + 128) * D_ + ko);
    rb2 = *reinterpret_cast<const uint4*>(kb + (size_t)(srow + 256) * D_ + ko);
    rb3 = *reinterpret_cast<const uint4*>(kb + (size_t)(srow + 384) * D_ + ko);
  };
  auto WRITE = [&](int nb) {
    if (tid < 256) *reinterpret_cast<uint4*>(&Asm[nb][wp]) = ra;
    *reinterpret_cast<uint4*>(&Bsm[nb][wp        ]) = rb0;   // rows 0-127
    *reinterpret_cast<uint4*>(&Bsm[nb][wp +  4096]) = rb1;   // +8 blocks
    *reinterpret_cast<uint4*>(&Bsm[nb][wp +  8192]) = rb2;
    *reinterpret_cast<uint4*>(&Bsm[nb][wp + 12288]) = rb3;
  };

  f32x4 acc[4][4];
#pragma unroll
  for (int i = 0; i < 4; ++i)
#pragma unroll
    for (int j = 0; j < 4; ++j) acc[i][j] = (f32x4){0.f, 0.f, 0.f, 0.f};

  LOAD(0); WRITE(0); __syncthreads();
  const int nst = D_ / 32;   // 32
  int cur = 0;
  for (int t = 0; t < nst; ++t) {
    if (t + 1 < nst) LOAD(t + 1);
    const ushort* As = Asm[cur];
    const ushort* Bs = Bsm[cur];
    bf16x8 af[4], bf[4];
#pragma unroll
    for (int i = 0; i < 4; ++i)
      af[i] = *reinterpret_cast<const bf16x8*>(As + (i * 64 + chunkLane) * 8);
#pragma unroll
    for (int j = 0; j < 4; ++j)
      bf[j] = *reinterpret_cast<const bf16x8*>(Bs + ((w * 4 + j) * 64 + chunkLane) * 8);
#pragma unroll
    for (int i = 0; i < 4; ++i)
#pragma unroll
      for (int j = 0; j < 4; ++j)
        acc[i][j] = __builtin_amdgcn_mfma_f32_16x16x32_bf16(af[i], bf[j], acc[i][j], 0, 0, 0);
    __syncthreads();
    if (t + 1 < nst) WRITE(cur ^ 1);
    __syncthreads();
    cur ^= 1;
  }

  // ---- softmax over full t (512) per i-row ----
  // C/D: row(i) = i*16 + g*4 + r, col(t) = w*64 + j*16 + lr
  const float c1 = 0.03125f * 1.44269504f;  // scale * log2(e)

  float mx[4][4];
#pragma unroll
  for (int i = 0; i < 4; ++i)
#pragma unroll
    for (int r = 0; r < 4; ++r) {
      float m = fmaxf(fmaxf(acc[i][0][r], acc[i][1][r]),
                      fmaxf(acc[i][2][r], acc[i][3][r]));
      m = fmaxf(m, __shfl_xor(m, 1));
      m = fmaxf(m, __shfl_xor(m, 2));
      m = fmaxf(m, __shfl_xor(m, 4));
      m = fmaxf(m, __shfl_xor(m, 8));
      mx[i][r] = m;
    }
  if (lr == 0) {
#pragma unroll
    for (int i = 0; i < 4; ++i)
#pragma unroll
      for (int r = 0; r < 4; ++r) redm[i * 16 + g * 4 + r][w] = mx[i][r];
  }
  __syncthreads();
  float gm[4][4];
#pragma unroll
  for (int i = 0; i < 4; ++i)
#pragma unroll
    for (int r = 0; r < 4; ++r) {
      const int row = i * 16 + g * 4 + r;
      const float4 a0 = *reinterpret_cast<const float4*>(&redm[row][0]);
      const float4 a1 = *reinterpret_cast<const float4*>(&redm[row][4]);
      gm[i][r] = fmaxf(fmaxf(fmaxf(a0.x, a0.y), fmaxf(a0.z, a0.w)),
                       fmaxf(fmaxf(a1.x, a1.y), fmaxf(a1.z, a1.w)));
    }

  float sm[4][4];
#pragma unroll
  for (int i = 0; i < 4; ++i)
#pragma unroll
    for (int r = 0; r < 4; ++r) sm[i][r] = 0.f;
#pragma unroll
  for (int i = 0; i < 4; ++i)
#pragma unroll
    for (int j = 0; j < 4; ++j)
#pragma unroll
      for (int r = 0; r < 4; ++r) {
        const float p = exp2f((acc[i][j][r] - gm[i][r]) * c1);
        acc[i][j][r] = p;
        sm[i][r] += p;
      }
#pragma unroll
  for (int i = 0; i < 4; ++i)
#pragma unroll
    for (int r = 0; r < 4; ++r) {
      float s = sm[i][r];
      s += __shfl_xor(s, 1);
      s += __shfl_xor(s, 2);
      s += __shfl_xor(s, 4);
      s += __shfl_xor(s, 8);
      sm[i][r] = s;
    }
  if (lr == 0) {
#pragma unroll
    for (int i = 0; i < 4; ++i)
#pragma unroll
      for (int r = 0; r < 4; ++r) reds[i * 16 + g * 4 + r][w] = sm[i][r];
  }
  __syncthreads();
  float inv[4][4];
#pragma unroll
  for (int i = 0; i < 4; ++i)
#pragma unroll
    for (int r = 0; r < 4; ++r) {
      const int row = i * 16 + g * 4 + r;
      const float4 a0 = *reinterpret_cast<const float4*>(&reds[row][0]);
      const float4 a1 = *reinterpret_cast<const float4*>(&reds[row][4]);
      inv[i][r] = 1.f / (a0.x + a0.y + a0.z + a0.w + a1.x + a1.y + a1.z + a1.w);
    }

  // ---- write attn in both layouts ----
#pragma unroll
  for (int i = 0; i < 4; ++i) {
    const int rbase = i0 + i * 16 + g * 4;
#pragma unroll
    for (int j = 0; j < 4; ++j) {
      const int tcol = w * 64 + j * 16 + lr;
      ushort4 pk;
      pk.x = f2b(acc[i][j][0] * inv[i][0]);
      pk.y = f2b(acc[i][j][1] * inv[i][1]);
      pk.z = f2b(acc[i][j][2] * inv[i][2]);
      pk.w = f2b(acc[i][j][3] * inv[i][3]);
      ushort* it_p = attn_it + ((size_t)b * NI_ + rbase) * NT_ + tcol;
      it_p[0 * NT_] = pk.x;
      it_p[1 * NT_] = pk.y;
      it_p[2 * NT_] = pk.z;
      it_p[3 * NT_] = pk.w;
      *reinterpret_cast<ushort4*>(attn_ti + ((size_t)b * NT_ + tcol) * NI_ + rbase) = pk;
    }
  }
}

// ---------------------------------------------------------------------------
// bt_gemm v6: C[m][n] = add[m][n] + sum_k A[m][k]*Bm[n][k].
// R3 reg-staged double-buffer structure, ONLY change: XOR-swizzled LDS.
// BK=32, 128x128 tile, 4 waves 2x2. grid (N/128, M/128, B), block 256.
// ---------------------------------------------------------------------------
__global__ __launch_bounds__(256) void bt_gemm_add_kernel(
    const ushort* __restrict__ A,   // [B][M][K] bf16
    const ushort* __restrict__ Bm,  // [B][N][K] bf16
    const float* __restrict__ add,  // [B][M][N] f32
    float* __restrict__ out,        // [B][M][N] f32
    int M, int N, int K)
{
  __shared__ __align__(16) ushort Asm[2][128 * 32];   // 2 x 8KB
  __shared__ __align__(16) ushort Bsm[2][128 * 32];   // 2 x 8KB

  const int b    = blockIdx.z;
  const int m0   = blockIdx.y * 128;
  const int n0   = blockIdx.x * 128;
  const int tid  = threadIdx.x;
  const int w    = tid >> 6;
  const int lane = tid & 63;
  const int lr   = lane & 15;
  const int g    = lane >> 4;

  const ushort* Ab = A  + ((size_t)b * M + m0) * K;
  const ushort* Bb = Bm + ((size_t)b * N + n0) * K;

  const int srow = tid >> 2;           // 0..63
  const int scol = (tid & 3) * 8;
  const int wp = (((tid >> 6) << 6) | (((tid >> 2) & 15) << 2)
                | ((tid & 3) ^ ((tid >> 3) & 3))) * 8;
  const int chunkLane = ((lane & 15) << 2) | ((lane >> 4) ^ ((lane >> 1) & 3));

  uint4 ra0, ra1, rbx0, rbx1;
  auto LOAD = [&](int t) {
    const int ko = t * 32 + scol;
    ra0  = *reinterpret_cast<const uint4*>(Ab + (size_t)(srow     ) * K + ko);
    ra1  = *reinterpret_cast<const uint4*>(Ab + (size_t)(srow + 64) * K + ko);
    rbx0 = *reinterpret_cast<const uint4*>(Bb + (size_t)(srow     ) * K + ko);
    rbx1 = *reinterpret_cast<const uint4*>(Bb + (size_t)(srow + 64) * K + ko);
  };
  auto WRITE = [&](int nb) {
    *reinterpret_cast<uint4*>(&Asm[nb][wp       ]) = ra0;
    *reinterpret_cast<uint4*>(&Asm[nb][wp + 2048]) = ra1;   // +4 blocks (rows+64)
    *reinterpret_cast<uint4*>(&Bsm[nb][wp       ]) = rbx0;
    *reinterpret_cast<uint4*>(&Bsm[nb][wp + 2048]) = rbx1;
  };

  f32x4 acc[4][4];
#pragma unroll
  for (int i = 0; i < 4; ++i)
#pragma unroll
    for (int j = 0; j < 4; ++j) acc[i][j] = (f32x4){0.f, 0.f, 0.f, 0.f};

  LOAD(0); WRITE(0); __syncthreads();
  const int nst = K / 32;
  int cur = 0;
  for (int t = 0; t < nst; ++t) {
    if (t + 1 < nst) LOAD(t + 1);
    const ushort* As = Asm[cur];
    const ushort* Bs = Bsm[cur];
    bf16x8 af[4], bf[4];
#pragma unroll
    for (int i = 0; i < 4; ++i)
      af[i] = *reinterpret_cast<const bf16x8*>(
          As + (((w >> 1) * 4 + i) * 64 + chunkLane) * 8);
#pragma unroll
    for (int j = 0; j < 4; ++j)
      bf[j] = *reinterpret_cast<const bf16x8*>(
          Bs + (((w & 1) * 4 + j) * 64 + chunkLane) * 8);
#pragma unroll
    for (int i = 0; i < 4; ++i)
#pragma unroll
      for (int j = 0; j < 4; ++j)
        acc[i][j] = __builtin_amdgcn_mfma_f32_16x16x32_bf16(af[i], bf[j], acc[i][j], 0, 0, 0);
    __syncthreads();
    if (t + 1 < nst) WRITE(cur ^ 1);
    __syncthreads();
    cur ^= 1;
  }

  const size_t ob = (size_t)b * M * N;
  const int rbase = m0 + (w >> 1) * 64 + g * 4;
#pragma unroll
  for (int i = 0; i < 4; ++i)
#pragma unroll
    for (int j = 0; j < 4; ++j) {
      const int c = n0 + (w & 1) * 64 + j * 16 + lr;
#pragma unroll
      for (int r = 0; r < 4; ++r) {
        const size_t idx = ob + (size_t)(rbase + i * 16 + r) * N + c;
        out[idx] = add[idx] + acc[i][j][r];
      }
    }
}

// ---------------------------------------------------------------------------
// Schedule (with buffer aliasing; requires ws_size >= 96 MB; observed ~768MB):
//   imn  (bf16 image_norm)  lives in out1 region of d_out
//   txn  (bf16 text_norm)   lives in out0 region of d_out (dead before out0)
//   ws: [attn_ti 32MB][attn_it 32MB][txnorm_T 32MB]; imnorm_T (64MB) reuses
//       attn_it+txnorm_T slots after the first GEMM consumes them.
// ---------------------------------------------------------------------------
extern "C" void kernel_launch(void* const* d_in, const int* in_sizes, int n_in,
                              void* d_out, int out_size, void* d_ws, size_t ws_size,
                              hipStream_t stream) {
  const float* imgf  = (const float*)d_in[0];
  const float* txtf  = (const float*)d_in[1];
  const float* gamma = (const float*)d_in[2];
  const float* beta  = (const float*)d_in[3];

  float* out0 = (float*)d_out;                       // [B][NI][D] f32
  float* out1 = out0 + (size_t)B_ * NI_ * D_;        // [B][NT][D] f32

  const size_t SZ = (size_t)B_ * NT_ * NI_ * 2;      // 33,554,432 B
  char* ws = (char*)d_ws;
  ushort* attn_ti = (ushort*)ws;                     // [B][NT][NI]
  ushort* attn_it = (ushort*)(ws + SZ);              // [B][NI][NT]
  ushort* txnT    = (ushort*)(ws + 2 * SZ);          // [B][D][NT]
  ushort* imnT    = (ushort*)(ws + SZ);              // [B][D][NI] (aliases attn_it+txnT)
  ushort* imn     = (ushort*)out1;                   // [B][NI][D] bf16 (scratch in out1)
  ushort* txn     = (ushort*)out0;                   // [B][NT][D] bf16 (scratch in out0)

  // 1-2: layernorms -> bf16
  ln_bf16_kernel<<<(B_ * NI_) / 4, 256, 0, stream>>>(imgf, gamma, beta, imn);
  ln_bf16_kernel<<<(B_ * NT_) / 4, 256, 0, stream>>>(txtf, gamma, beta, txn);
  // 3: QK^T + softmax -> attn in both layouts (512 blocks, XCD-swizzled)
  qk_softmax_kernel<<<(NI_ / 64) * B_, 512, 0, stream>>>(imn, txn, attn_it, attn_ti);
  // 4: text_norm^T
  transpose_bf16_kernel<<<dim3(D_ / 64, NT_ / 64, B_), 256, 0, stream>>>(txn, txnT, NT_, D_);
  // 5: out0 = image + attn @ text_norm   (overwrites txn scratch — dead)
  bt_gemm_add_kernel<<<dim3(D_ / 128, NI_ / 128, B_), 256, 0, stream>>>(
      attn_it, txnT, imgf, out0, NI_, D_, NT_);
  // 6: image_norm^T (overwrites attn_it + txnT — dead)
  transpose_bf16_kernel<<<dim3(D_ / 64, NI_ / 64, B_), 256, 0, stream>>>(imn, imnT, NI_, D_);
  // 7: out1 = text + attn^T @ image_norm (overwrites imn scratch — dead)
  bt_gemm_add_kernel<<<dim3(D_ / 128, NT_ / 128, B_), 256, 0, stream>>>(
      attn_ti, imnT, txtf, out1, NT_, D_, NI_);
}